// Round 4
// baseline (1071.596 us; speedup 1.0000x reference)
//
#include <hip/hip_runtime.h>

#define TB 512   // batch
#define TT 1024  // time
#define TD 64    // input dim
#define TH 128   // hidden
#define NR 4     // batch rows per block -> 128 blocks, 1 per CU (of 256)

typedef __attribute__((ext_vector_type(8))) short short8;  // 8 bf16 (4 VGPRs)
typedef __attribute__((ext_vector_type(4))) float f32x4;   // MFMA C/D
typedef __attribute__((ext_vector_type(2))) float f32x2;
typedef __attribute__((ext_vector_type(4))) short s16x4;   // 4 bf16 (8B)

#define LOG2E 1.44269504f

// fp32 -> bf16 bits, round-to-nearest-even
__device__ __forceinline__ short bfb(float f) {
    unsigned u = __builtin_bit_cast(unsigned, f);
    u = (u + 0x7FFFu + ((u >> 16) & 1u)) >> 16;
    return (short)u;
}

// Barrier with LDS-only drain: global loads/stores stay in flight across it.
#define BAR() asm volatile("s_waitcnt lgkmcnt(0)\n\ts_barrier" ::: "memory")

#define MFMA(a, b, cc) __builtin_amdgcn_mfma_f32_16x16x32_bf16(a, b, cc, 0, 0, 0)

// ---------------- phase 1: x -> bf16 fragment order (compact, 4 rows) -------
// ws layout (short8 units): [blk 0..127][t][kt 0..1][e 0..15], e = c*4 + quad
// holds x[blk*4 + c][t][32*kt + 8*quad + j], j=0..7
__global__ __launch_bounds__(256)
void xswz(const float* __restrict__ x, short8* __restrict__ ws) {
    int gid = blockIdx.x * 256 + threadIdx.x;   // 128*1024*2*16 = 4.19M
    int e   = gid & 15;
    int kt  = (gid >> 4) & 1;
    int t   = (gid >> 5) & (TT - 1);
    int blk = gid >> 15;
    int c = e >> 2, quad = e & 3;
    const float* p = x + ((size_t)(blk * NR + c) * TT + t) * TD + 32 * kt + 8 * quad;
    f32x4 a = *(const f32x4*)p;
    f32x4 b = *(const f32x4*)(p + 4);
    short8 f;
    #pragma unroll
    for (int j = 0; j < 4; ++j) { f[j] = bfb(a[j]); f[4 + j] = bfb(b[j]); }
    ws[gid] = f;
}

// ---------------- phase 2: the scan -----------------------------------------
// 128 blocks x 512 threads. Block owns 4 batch rows.
// TRANSPOSED MFMA: C' = W_tile * h^T (weights as A-operand, h/x as B-operand;
// the per-lane load formulas for A- and B-frags are identical, so no load
// changes). C'[4q+r][c] = gate-col 16w+4q+r, batch c: each lane owns 4 gate
// columns of ONE batch row in its own accumulator regs -> the epilogue runs
// 4-wide fully in-register and the exws LDS exchange roundtrip is GONE.
// Lanes c>=4 compute quarantined garbage (never stored). h-write is one
// ds_write_b64 of 4 contiguous bf16 per (c<4) lane, conflict-free.
template <bool USE_WS>
__global__ __launch_bounds__(512, 1)
void gru_mfma(const float* __restrict__ x, const short8* __restrict__ xw,
              const float* __restrict__ mask,
              const float* __restrict__ w_ih, const float* __restrict__ w_hh,
              const float* __restrict__ b_ih, const float* __restrict__ b_hh,
              const float* __restrict__ Wo, const float* __restrict__ bo,
              float* __restrict__ out)
{
    __shared__ short hbuf[2][4][144];     // h(t) bf16, rows 0..3; 288B row
                                          // stride -> uniform 2-way on b128
    __shared__ float mlds[TT][NR];        // mask slice (16 KB)

    const int tid  = threadIdx.x;
    const int w    = tid >> 6;
    const int lane = tid & 63;
    const int c    = lane & 15;
    const int quad = lane >> 4;
    const int Bb   = blockIdx.x * NR;

    // ---- one-time staging ----
    for (int i = tid; i < TT * NR; i += 512) {
        int t = i >> 2, b = i & 3;
        mlds[t][b] = mask[(size_t)(Bb + b) * TT + t];
    }
    for (int i = tid; i < 2 * 4 * 144; i += 512) (&hbuf[0][0][0])[i] = 0;

    const int jj = 16 * w + c;            // gate column for weight loads

    // ---- weights -> bf16 fragments in registers (unchanged loads) ----
    short8 whh[3][4], wih[3][2], wof[4];
    {
        const int gg[3] = {jj, TH + jj, 2 * TH + jj};
        #pragma unroll
        for (int g = 0; g < 3; ++g) {
            #pragma unroll
            for (int kt = 0; kt < 4; ++kt) {
                const float* p = w_hh + (size_t)gg[g] * TH + 32 * kt + 8 * quad;
                short8 f;
                #pragma unroll
                for (int j = 0; j < 8; ++j) f[j] = bfb(p[j]);
                whh[g][kt] = f;
            }
            #pragma unroll
            for (int kt = 0; kt < 2; ++kt) {
                const float* p = w_ih + (size_t)gg[g] * TD + 32 * kt + 8 * quad;
                short8 f;
                #pragma unroll
                for (int j = 0; j < 8; ++j) f[j] = bfb(p[j]);
                wih[g][kt] = f;
            }
        }
        #pragma unroll
        for (int kt = 0; kt < 4; ++kt) {
            short8 f = {0,0,0,0,0,0,0,0};
            if (c < 2) {
                const float* p = Wo + (size_t)c * TH + 32 * kt + 8 * quad;
                #pragma unroll
                for (int j = 0; j < 8; ++j) f[j] = bfb(p[j]);
            }
            wof[kt] = f;
        }
    }

    // epilogue constants: this lane owns gate cols col0..col0+3 (batch = c)
    f32x4 crK4, czK4, bin4, bhn4;
    {
        const int col0 = 16 * w + 4 * quad;
        #pragma unroll
        for (int r2 = 0; r2 < 4; ++r2) {
            crK4[r2] = -LOG2E * (b_ih[col0 + r2] + b_hh[col0 + r2]);
            czK4[r2] = -LOG2E * (b_ih[TH + col0 + r2] + b_hh[TH + col0 + r2]);
            bin4[r2] = b_ih[2 * TH + col0 + r2];
            bhn4[r2] = b_hh[2 * TH + col0 + r2];
        }
    }
    const float b0o = bo[0], b1o = bo[1];

    const short8 z8  = {0,0,0,0,0,0,0,0};
    const f32x4  zf4 = {0.f, 0.f, 0.f, 0.f};

    // x access bases (fragment data unchanged; now consumed as B-operand)
    const short8* xwp  = xw + (size_t)blockIdx.x * (TT * 32) + (c * 4 + quad);
    const float*  xrow = x + (size_t)(Bb + (c < 4 ? c : 0)) * TT * TD + 8 * quad;

    short8 xf0[2], xf1[2];
    // frags(0) -> xf0
    if (USE_WS) {
        xf0[0] = (c < 4) ? xwp[0]  : z8;
        xf0[1] = (c < 4) ? xwp[16] : z8;
    } else {
        #pragma unroll
        for (int kt = 0; kt < 2; ++kt) {
            f32x4 a = *(const f32x4*)(xrow + 32 * kt);
            f32x4 b = *(const f32x4*)(xrow + 32 * kt + 4);
            short8 f = z8;
            if (c < 4) {
                #pragma unroll
                for (int j = 0; j < 4; ++j) { f[j] = bfb(a[j]); f[4 + j] = bfb(b[j]); }
            }
            xf0[kt] = f;
        }
    }

    // xacc(0) from frags(0)  (W_ih as A-operand, x as B-operand)
    f32x4 xacA[3], xacB[3];
    #pragma unroll
    for (int g = 0; g < 3; ++g) {
        f32x4 a = zf4;
        a = MFMA(wih[g][0], xf0[0], a);
        a = MFMA(wih[g][1], xf0[1], a);
        xacA[g] = a;
    }

    // frags(1) -> xf0
    if (USE_WS) {
        xf0[0] = (c < 4) ? xwp[32] : z8;
        xf0[1] = (c < 4) ? xwp[48] : z8;
    } else {
        const float* p = xrow + (size_t)1 * TD;
        #pragma unroll
        for (int kt = 0; kt < 2; ++kt) {
            f32x4 a = *(const f32x4*)(p + 32 * kt);
            f32x4 b = *(const f32x4*)(p + 32 * kt + 4);
            short8 f = z8;
            if (c < 4) {
                #pragma unroll
                for (int j = 0; j < 4; ++j) { f[j] = bfb(a[j]); f[4 + j] = bfb(b[j]); }
            }
            xf0[kt] = f;
        }
    }

    f32x4 hold4 = zf4;   // fp32 h for (batch=c, cols col0..col0+3)

// Invariants entering STEP(t): AC = xacc(t); XC = frags(t+1) (in flight).
// STEP(t) issues loads for frags(t+2) into XN and builds AN = xacc(t+1).
#define STEP(T, XC, XN, AC, AN)                                                 \
  {                                                                             \
    const int t = (T);                                                          \
    BAR();                                                                      \
    const int rb = t & 1, wb = rb ^ 1;                                          \
    short8 ha[4];                                                               \
    _Pragma("unroll")                                                           \
    for (int kt = 0; kt < 4; ++kt)                                              \
        ha[kt] = *(const short8*)(&hbuf[rb][c & 3][32 * kt + 8 * quad]);        \
    const float m = mlds[t][c & 3];       /* issued early, hides under MFMAs */ \
    const int tn = (t + 2 < TT) ? t + 2 : TT - 1;                               \
    f32x4 nxa0, nxb0, nxa1, nxb1;                                               \
    if (USE_WS) {                                                               \
        XN[0] = (c < 4) ? xwp[(size_t)tn * 32]      : z8;                       \
        XN[1] = (c < 4) ? xwp[(size_t)tn * 32 + 16] : z8;                       \
    } else {                                                                    \
        const float* p = xrow + (size_t)tn * TD;                                \
        nxa0 = *(const f32x4*)(p);      nxb0 = *(const f32x4*)(p + 4);          \
        nxa1 = *(const f32x4*)(p + 32); nxb1 = *(const f32x4*)(p + 36);         \
    }                                                                           \
    /* h-MFMAs (transposed): two 2-deep chains per gate */                      \
    f32x4 rA = AC[0], zA = AC[1], nA = zf4;                                     \
    f32x4 rB = zf4, zB = zf4, nB = zf4;                                         \
    rA = MFMA(whh[0][0], ha[0], rA);                                            \
    zA = MFMA(whh[1][0], ha[0], zA);                                            \
    nA = MFMA(whh[2][0], ha[0], nA);                                            \
    rB = MFMA(whh[0][2], ha[2], rB);                                            \
    zB = MFMA(whh[1][2], ha[2], zB);                                            \
    nB = MFMA(whh[2][2], ha[2], nB);                                            \
    rA = MFMA(whh[0][1], ha[1], rA);                                            \
    zA = MFMA(whh[1][1], ha[1], zA);                                            \
    nA = MFMA(whh[2][1], ha[1], nA);                                            \
    rB = MFMA(whh[0][3], ha[3], rB);                                            \
    zB = MFMA(whh[1][3], ha[3], zB);                                            \
    nB = MFMA(whh[2][3], ha[3], nB);                                            \
    /* logits for t-1 (rotating wave): rows 0,1 = Wo rows, col = batch */       \
    if (t > 0 && w == ((t - 1) & 7)) {                                          \
        f32x4 lacc = zf4;                                                       \
        _Pragma("unroll")                                                       \
        for (int kt = 0; kt < 4; ++kt) lacc = MFMA(wof[kt], ha[kt], lacc);      \
        if (quad == 0 && c < 4) {                                               \
            f32x2 lo = {lacc[0] + b0o, lacc[1] + b1o};                          \
            *(f32x2*)(out + ((size_t)(Bb + c) * TT + (t - 1)) * 2) = lo;        \
        }                                                                       \
    }                                                                           \
    /* next step's x-gate accumulators (overlap h-chain completion) */          \
    _Pragma("unroll")                                                           \
    for (int g = 0; g < 3; ++g) {                                               \
        f32x4 a = zf4;                                                          \
        a = MFMA(wih[g][0], XC[0], a);                                          \
        a = MFMA(wih[g][1], XC[1], a);                                          \
        AN[g] = a;                                                              \
    }                                                                           \
    /* in-register epilogue, 4 independent columns (no LDS exchange!) */        \
    {                                                                           \
        f32x4 arS = rA + rB, azS = zA + zB, anhS = nA + nB, anxS = AC[2];       \
        s16x4 hw;                                                               \
        _Pragma("unroll")                                                       \
        for (int r2 = 0; r2 < 4; ++r2) {                                        \
            float er = __builtin_amdgcn_exp2f(__builtin_fmaf(arS[r2], -LOG2E, crK4[r2])); \
            float r  = __builtin_amdgcn_rcpf(1.0f + er);                        \
            float ez = __builtin_amdgcn_exp2f(__builtin_fmaf(azS[r2], -LOG2E, czK4[r2])); \
            float z  = __builtin_amdgcn_rcpf(1.0f + ez);                        \
            float pp = (anxS[r2] + bin4[r2]) + r * (anhS[r2] + bhn4[r2]);       \
            float e2 = __builtin_amdgcn_exp2f(pp * (2.0f * LOG2E));             \
            float n  = __builtin_fmaf(-2.0f, __builtin_amdgcn_rcpf(1.0f + e2), 1.0f); \
            float hn = n + z * (hold4[r2] - n);                                 \
            hold4[r2] = hold4[r2] + m * (hn - hold4[r2]);                       \
            hw[r2] = bfb(hold4[r2]);                                            \
        }                                                                       \
        if (c < 4) *(s16x4*)(&hbuf[wb][c][16 * w + 4 * quad]) = hw;             \
    }                                                                           \
    if (!USE_WS) {                                                              \
        short8 f0 = z8, f1 = z8;                                                \
        if (c < 4) {                                                            \
            _Pragma("unroll")                                                   \
            for (int j = 0; j < 4; ++j) { f0[j] = bfb(nxa0[j]); f0[4+j] = bfb(nxb0[j]); \
                                          f1[j] = bfb(nxa1[j]); f1[4+j] = bfb(nxb1[j]); } \
        }                                                                       \
        XN[0] = f0; XN[1] = f1;                                                 \
    }                                                                           \
  }

    for (int t2 = 0; t2 < TT; t2 += 2) {
        STEP(t2,     xf0, xf1, xacA, xacB);
        STEP(t2 + 1, xf1, xf0, xacB, xacA);
    }
#undef STEP

    // flush logits for t = TT-1 (h(TT-1) sits in hbuf[0])
    BAR();
    if (w == 7) {
        short8 ha[4];
        #pragma unroll
        for (int kt = 0; kt < 4; ++kt)
            ha[kt] = *(const short8*)(&hbuf[0][c & 3][32 * kt + 8 * quad]);
        f32x4 lacc = zf4;
        #pragma unroll
        for (int kt = 0; kt < 4; ++kt) lacc = MFMA(wof[kt], ha[kt], lacc);
        if (quad == 0 && c < 4) {
            f32x2 lo = {lacc[0] + b0o, lacc[1] + b1o};
            *(f32x2*)(out + ((size_t)(Bb + c) * TT + (TT - 1)) * 2) = lo;
        }
    }
}

extern "C" void kernel_launch(void* const* d_in, const int* in_sizes, int n_in,
                              void* d_out, int out_size, void* d_ws, size_t ws_size,
                              hipStream_t stream) {
    const float* x    = (const float*)d_in[0];
    const float* mask = (const float*)d_in[1];
    const float* w_ih = (const float*)d_in[2];
    const float* w_hh = (const float*)d_in[3];
    const float* b_ih = (const float*)d_in[4];
    const float* b_hh = (const float*)d_in[5];
    const float* Wo   = (const float*)d_in[6];
    const float* bo   = (const float*)d_in[7];
    float* out = (float*)d_out;
    (void)in_sizes; (void)n_in; (void)out_size;

    const size_t nfrag = (size_t)(TB / NR) * TT * 2 * 16;       // 4.19M short8
    const size_t need  = nfrag * sizeof(short8);                // 67.1 MB
    if (ws_size >= need) {
        short8* xw = (short8*)d_ws;
        xswz<<<(int)(nfrag / 256), 256, 0, stream>>>(x, xw);
        gru_mfma<true><<<TB / NR, 512, 0, stream>>>(x, xw, mask, w_ih, w_hh,
                                                    b_ih, b_hh, Wo, bo, out);
    } else {
        gru_mfma<false><<<TB / NR, 512, 0, stream>>>(x, (const short8*)nullptr, mask,
                                                     w_ih, w_hh, b_ih, b_hh, Wo, bo, out);
    }
}

// Round 5
// 740.366 us; speedup vs baseline: 1.4474x; 1.4474x over previous
//
#include <hip/hip_runtime.h>

#define TB 512   // batch
#define TT 1024  // time
#define TD 64    // input dim
#define TH 128   // hidden
#define NR 4     // batch rows per block -> 128 blocks, 1 per CU (of 256)

typedef __attribute__((ext_vector_type(8))) short short8;  // 8 bf16 (4 VGPRs)
typedef __attribute__((ext_vector_type(4))) float f32x4;   // MFMA C/D
typedef __attribute__((ext_vector_type(2))) float f32x2;

#define LOG2E 1.44269504f

// fp32 -> bf16 bits, round-to-nearest-even
__device__ __forceinline__ short bfb(float f) {
    unsigned u = __builtin_bit_cast(unsigned, f);
    u = (u + 0x7FFFu + ((u >> 16) & 1u)) >> 16;
    return (short)u;
}

// Barrier with LDS-only drain: global loads/stores stay in flight across it.
#define BAR() asm volatile("s_waitcnt lgkmcnt(0)\n\ts_barrier" ::: "memory")

#define MFMA(a, b, cc) __builtin_amdgcn_mfma_f32_16x16x32_bf16(a, b, cc, 0, 0, 0)

// select v[r], r = s1*2 + s0, via 3 cndmasks (bools precomputed per lane)
__device__ __forceinline__ float ext4(f32x4 v, bool s0, bool s1) {
    float a = s0 ? v[1] : v[0];
    float b = s0 ? v[3] : v[2];
    return s1 ? b : a;
}

// ---------------- phase 1: x -> bf16 fragment order (compact, 4 rows) -------
// ws layout (short8 units): [blk 0..127][t][kt 0..1][e 0..15], e = c*4 + quad
// holds x[blk*4 + c][t][32*kt + 8*quad + j], j=0..7
__global__ __launch_bounds__(256)
void xswz(const float* __restrict__ x, short8* __restrict__ ws) {
    int gid = blockIdx.x * 256 + threadIdx.x;   // 128*1024*2*16 = 4.19M
    int e   = gid & 15;
    int kt  = (gid >> 4) & 1;
    int t   = (gid >> 5) & (TT - 1);
    int blk = gid >> 15;
    int c = e >> 2, quad = e & 3;
    const float* p = x + ((size_t)(blk * NR + c) * TT + t) * TD + 32 * kt + 8 * quad;
    f32x4 a = *(const f32x4*)p;
    f32x4 b = *(const f32x4*)(p + 4);
    short8 f;
    #pragma unroll
    for (int j = 0; j < 4; ++j) { f[j] = bfb(a[j]); f[4 + j] = bfb(b[j]); }
    ws[gid] = f;
}

// ---------------- phase 2: the scan -----------------------------------------
// 128 blocks x 512 threads. Block owns 4 batch rows.
// TRANSPOSED MFMA (C' = W_tile * h^T) with REPLICATED B-operand: all lanes
// read batch row (c&3), so lane (c,q)'s accumulator quad is replicated 4x
// across c-groups. Lane (c,q) therefore owns the REAL value at reg r = c>>2:
// (gate col 16w+4q+(c>>2), batch c&3) -- 64 lanes x 1 value = the wave's full
// 16-col x 4-batch tile. Epilogue is ONE chain per lane (3-cndmask extract),
// no LDS exchange at all. DS instrs per CU per step: 48 (was 112 in exws ver).
template <bool USE_WS>
__global__ __launch_bounds__(512, 1)
void gru_mfma(const float* __restrict__ x, const short8* __restrict__ xw,
              const float* __restrict__ mask,
              const float* __restrict__ w_ih, const float* __restrict__ w_hh,
              const float* __restrict__ b_ih, const float* __restrict__ b_hh,
              const float* __restrict__ Wo, const float* __restrict__ bo,
              float* __restrict__ out)
{
    __shared__ short hbuf[2][4][144];     // h(t) bf16, rows 0..3; 288B row
                                          // stride -> <=2-way on reads (free)
    __shared__ float mlds[TT][NR];        // mask slice (16 KB)

    const int tid  = threadIdx.x;
    const int w    = tid >> 6;
    const int lane = tid & 63;
    const int c    = lane & 15;
    const int quad = lane >> 4;
    const int Bb   = blockIdx.x * NR;
    const int cb   = c & 3;               // batch row this lane tracks
    const bool s0  = ((c >> 2) & 1) != 0; // extract selectors for reg c>>2
    const bool s1  = ((c >> 3) & 1) != 0;

    // ---- one-time staging ----
    for (int i = tid; i < TT * NR; i += 512) {
        int t = i >> 2, b = i & 3;
        mlds[t][b] = mask[(size_t)(Bb + b) * TT + t];
    }
    for (int i = tid; i < 2 * 4 * 144; i += 512) (&hbuf[0][0][0])[i] = 0;

    const int jj = 16 * w + c;            // weight-fragment row/col key

    // ---- weights -> bf16 fragments in registers (unchanged loads) ----
    short8 whh[3][4], wih[3][2], wof[4];
    {
        const int gg[3] = {jj, TH + jj, 2 * TH + jj};
        #pragma unroll
        for (int g = 0; g < 3; ++g) {
            #pragma unroll
            for (int kt = 0; kt < 4; ++kt) {
                const float* p = w_hh + (size_t)gg[g] * TH + 32 * kt + 8 * quad;
                short8 f;
                #pragma unroll
                for (int j = 0; j < 8; ++j) f[j] = bfb(p[j]);
                whh[g][kt] = f;
            }
            #pragma unroll
            for (int kt = 0; kt < 2; ++kt) {
                const float* p = w_ih + (size_t)gg[g] * TD + 32 * kt + 8 * quad;
                short8 f;
                #pragma unroll
                for (int j = 0; j < 8; ++j) f[j] = bfb(p[j]);
                wih[g][kt] = f;
            }
        }
        #pragma unroll
        for (int kt = 0; kt < 4; ++kt) {
            short8 f = {0,0,0,0,0,0,0,0};
            if (c < 2) {
                const float* p = Wo + (size_t)c * TH + 32 * kt + 8 * quad;
                #pragma unroll
                for (int j = 0; j < 8; ++j) f[j] = bfb(p[j]);
            }
            wof[kt] = f;
        }
    }

    // epilogue constants for THIS lane's gate column myc (scalar, like R2)
    const int myc = 16 * w + 4 * quad + (c >> 2);
    const float crK = -LOG2E * (b_ih[myc] + b_hh[myc]);
    const float czK = -LOG2E * (b_ih[TH + myc] + b_hh[TH + myc]);
    const float bin = b_ih[2 * TH + myc];
    const float bhn = b_hh[2 * TH + myc];
    const float b0o = bo[0], b1o = bo[1];

    const short8 z8  = {0,0,0,0,0,0,0,0};
    const f32x4  zf4 = {0.f, 0.f, 0.f, 0.f};

    // x access bases — REPLICATED across c-groups (row c&3) so the x-gate
    // accumulators are valid on all lanes (same cache lines, stays coalesced)
    const short8* xwp  = xw + (size_t)blockIdx.x * (TT * 32) + (cb * 4 + quad);
    const float*  xrow = x + (size_t)(Bb + cb) * TT * TD + 8 * quad;

    short8 xf0[2], xf1[2];
    // frags(0) -> xf0
    if (USE_WS) {
        xf0[0] = xwp[0];
        xf0[1] = xwp[16];
    } else {
        #pragma unroll
        for (int kt = 0; kt < 2; ++kt) {
            f32x4 a = *(const f32x4*)(xrow + 32 * kt);
            f32x4 b = *(const f32x4*)(xrow + 32 * kt + 4);
            short8 f;
            #pragma unroll
            for (int j = 0; j < 4; ++j) { f[j] = bfb(a[j]); f[4 + j] = bfb(b[j]); }
            xf0[kt] = f;
        }
    }

    // xacc(0) from frags(0)  (W_ih as A-operand, x as B-operand)
    f32x4 xacA[3], xacB[3];
    #pragma unroll
    for (int g = 0; g < 3; ++g) {
        f32x4 a = zf4;
        a = MFMA(wih[g][0], xf0[0], a);
        a = MFMA(wih[g][1], xf0[1], a);
        xacA[g] = a;
    }

    // frags(1) -> xf0
    if (USE_WS) {
        xf0[0] = xwp[32];
        xf0[1] = xwp[48];
    } else {
        const float* p = xrow + (size_t)1 * TD;
        #pragma unroll
        for (int kt = 0; kt < 2; ++kt) {
            f32x4 a = *(const f32x4*)(p + 32 * kt);
            f32x4 b = *(const f32x4*)(p + 32 * kt + 4);
            short8 f;
            #pragma unroll
            for (int j = 0; j < 4; ++j) { f[j] = bfb(a[j]); f[4 + j] = bfb(b[j]); }
            xf0[kt] = f;
        }
    }

    float hold = 0.0f;   // fp32 h for (batch=cb, col=myc)

// Invariants entering STEP(t): AC = xacc(t); XC = frags(t+1) (in flight).
// STEP(t) issues loads for frags(t+2) into XN and builds AN = xacc(t+1).
#define STEP(T, XC, XN, AC, AN)                                                 \
  {                                                                             \
    const int t = (T);                                                          \
    BAR();                                                                      \
    const int rb = t & 1, wb = rb ^ 1;                                          \
    short8 ha[4];                                                               \
    _Pragma("unroll")                                                           \
    for (int kt = 0; kt < 4; ++kt)                                              \
        ha[kt] = *(const short8*)(&hbuf[rb][cb][32 * kt + 8 * quad]);           \
    const float m = mlds[t][cb];          /* issued early, hides under MFMAs */ \
    const int tn = (t + 2 < TT) ? t + 2 : TT - 1;                               \
    f32x4 nxa0, nxb0, nxa1, nxb1;                                               \
    if (USE_WS) {                                                               \
        XN[0] = xwp[(size_t)tn * 32];                                           \
        XN[1] = xwp[(size_t)tn * 32 + 16];                                      \
    } else {                                                                    \
        const float* p = xrow + (size_t)tn * TD;                                \
        nxa0 = *(const f32x4*)(p);      nxb0 = *(const f32x4*)(p + 4);          \
        nxa1 = *(const f32x4*)(p + 32); nxb1 = *(const f32x4*)(p + 36);         \
    }                                                                           \
    /* h-MFMAs (transposed): two 2-deep chains per gate */                      \
    f32x4 rA = AC[0], zA = AC[1], nA = zf4;                                     \
    f32x4 rB = zf4, zB = zf4, nB = zf4;                                         \
    rA = MFMA(whh[0][0], ha[0], rA);                                            \
    zA = MFMA(whh[1][0], ha[0], zA);                                            \
    nA = MFMA(whh[2][0], ha[0], nA);                                            \
    rB = MFMA(whh[0][2], ha[2], rB);                                            \
    zB = MFMA(whh[1][2], ha[2], zB);                                            \
    nB = MFMA(whh[2][2], ha[2], nB);                                            \
    rA = MFMA(whh[0][1], ha[1], rA);                                            \
    zA = MFMA(whh[1][1], ha[1], zA);                                            \
    nA = MFMA(whh[2][1], ha[1], nA);                                            \
    rB = MFMA(whh[0][3], ha[3], rB);                                            \
    zB = MFMA(whh[1][3], ha[3], zB);                                            \
    nB = MFMA(whh[2][3], ha[3], nB);                                            \
    /* logits for t-1 (rotating wave): rows 0,1 = Wo rows, col = batch */       \
    if (t > 0 && w == ((t - 1) & 7)) {                                          \
        f32x4 lacc = zf4;                                                       \
        _Pragma("unroll")                                                       \
        for (int kt = 0; kt < 4; ++kt) lacc = MFMA(wof[kt], ha[kt], lacc);      \
        if (quad == 0 && c < 4) {                                               \
            f32x2 lo = {lacc[0] + b0o, lacc[1] + b1o};                          \
            *(f32x2*)(out + ((size_t)(Bb + c) * TT + (t - 1)) * 2) = lo;        \
        }                                                                       \
    }                                                                           \
    /* next step's x-gate accumulators (overlap h-chain completion) */          \
    _Pragma("unroll")                                                           \
    for (int g = 0; g < 3; ++g) {                                               \
        f32x4 a = zf4;                                                          \
        a = MFMA(wih[g][0], XC[0], a);                                          \
        a = MFMA(wih[g][1], XC[1], a);                                          \
        AN[g] = a;                                                              \
    }                                                                           \
    /* scalar epilogue: this lane's (batch cb, col myc) = reg c>>2 */           \
    {                                                                           \
        float arS  = ext4(rA + rB, s0, s1);                                     \
        float azS  = ext4(zA + zB, s0, s1);                                     \
        float anhS = ext4(nA + nB, s0, s1);                                     \
        float anxS = ext4(AC[2],   s0, s1);                                     \
        float er = __builtin_amdgcn_exp2f(__builtin_fmaf(arS, -LOG2E, crK));    \
        float r  = __builtin_amdgcn_rcpf(1.0f + er);                            \
        float ez = __builtin_amdgcn_exp2f(__builtin_fmaf(azS, -LOG2E, czK));    \
        float z  = __builtin_amdgcn_rcpf(1.0f + ez);                            \
        float pp = (anxS + bin) + r * (anhS + bhn);                             \
        float e2 = __builtin_amdgcn_exp2f(pp * (2.0f * LOG2E));                 \
        float n  = __builtin_fmaf(-2.0f, __builtin_amdgcn_rcpf(1.0f + e2), 1.0f); \
        float hn = n + z * (hold - n);                                          \
        hold = hold + m * (hn - hold);                                          \
        hbuf[wb][cb][myc] = bfb(hold);                                          \
    }                                                                           \
    if (!USE_WS) {                                                              \
        short8 f0, f1;                                                          \
        _Pragma("unroll")                                                       \
        for (int j = 0; j < 4; ++j) { f0[j] = bfb(nxa0[j]); f0[4+j] = bfb(nxb0[j]); \
                                      f1[j] = bfb(nxa1[j]); f1[4+j] = bfb(nxb1[j]); } \
        XN[0] = f0; XN[1] = f1;                                                 \
    }                                                                           \
  }

    for (int t2 = 0; t2 < TT; t2 += 2) {
        STEP(t2,     xf0, xf1, xacA, xacB);
        STEP(t2 + 1, xf1, xf0, xacB, xacA);
    }
#undef STEP

    // flush logits for t = TT-1 (h(TT-1) sits in hbuf[0])
    BAR();
    if (w == 7) {
        short8 ha[4];
        #pragma unroll
        for (int kt = 0; kt < 4; ++kt)
            ha[kt] = *(const short8*)(&hbuf[0][cb][32 * kt + 8 * quad]);
        f32x4 lacc = zf4;
        #pragma unroll
        for (int kt = 0; kt < 4; ++kt) lacc = MFMA(wof[kt], ha[kt], lacc);
        if (quad == 0 && c < 4) {
            f32x2 lo = {lacc[0] + b0o, lacc[1] + b1o};
            *(f32x2*)(out + ((size_t)(Bb + c) * TT + (TT - 1)) * 2) = lo;
        }
    }
}

extern "C" void kernel_launch(void* const* d_in, const int* in_sizes, int n_in,
                              void* d_out, int out_size, void* d_ws, size_t ws_size,
                              hipStream_t stream) {
    const float* x    = (const float*)d_in[0];
    const float* mask = (const float*)d_in[1];
    const float* w_ih = (const float*)d_in[2];
    const float* w_hh = (const float*)d_in[3];
    const float* b_ih = (const float*)d_in[4];
    const float* b_hh = (const float*)d_in[5];
    const float* Wo   = (const float*)d_in[6];
    const float* bo   = (const float*)d_in[7];
    float* out = (float*)d_out;
    (void)in_sizes; (void)n_in; (void)out_size;

    const size_t nfrag = (size_t)(TB / NR) * TT * 2 * 16;       // 4.19M short8
    const size_t need  = nfrag * sizeof(short8);                // 67.1 MB
    if (ws_size >= need) {
        short8* xw = (short8*)d_ws;
        xswz<<<(int)(nfrag / 256), 256, 0, stream>>>(x, xw);
        gru_mfma<true><<<TB / NR, 512, 0, stream>>>(x, xw, mask, w_ih, w_hh,
                                                    b_ih, b_hh, Wo, bo, out);
    } else {
        gru_mfma<false><<<TB / NR, 512, 0, stream>>>(x, (const short8*)nullptr, mask,
                                                     w_ih, w_hh, b_ih, b_hh, Wo, bo, out);
    }
}